// Round 3
// baseline (4951.944 us; speedup 1.0000x reference)
//
#include <hip/hip_runtime.h>
#include <stdint.h>

typedef unsigned short bf16_t;

constexpr int kNN   = 100000;
constexpr int kNE   = 1600000;
constexpr int kFEAT = 256;
constexpr int kHID  = 128;
constexpr int kOUT  = 64;
constexpr int kNB   = 10000;
constexpr float kEPS = 1e-5f;

__device__ __forceinline__ float bf2f(bf16_t u) {
    union { uint32_t i; float f; } v; v.i = ((uint32_t)u) << 16; return v.f;
}
__device__ __forceinline__ bf16_t f2bf(float f) {
    uint32_t u = __float_as_uint(f);
    uint32_t r = (u + 0x7FFFu + ((u >> 16) & 1u)) >> 16;
    return (bf16_t)r;
}

// flags[0]: 1 if float tensors are stored bf16, 0 if fp32
// flags[1]: 1 if edge_index is int64, 0 if int32
__global__ void k_probe(const uint32_t* __restrict__ feat, const uint32_t* __restrict__ ei,
                        int* __restrict__ flags) {
    if (blockIdx.x == 0 && threadIdx.x == 0) {
        int good = 0;
        for (int j = 0; j < 256; j++) {
            uint32_t u = feat[j];
            uint32_t e = (u >> 7) & 0xFFu;  // low half as bf16: exponent field
            if (e >= 100u && e <= 132u) good++;
        }
        flags[0] = (good > 128) ? 1 : 0;
        int zeros = 0;
        for (int j = 0; j < 128; j++) {
            if (ei[2 * j + 1] == 0u) zeros++;  // int64 high words are 0
        }
        flags[1] = (zeros > 64) ? 1 : 0;
    }
}

// sentinel: uniform log-softmax everywhere; distinguishes "never ran" from "died later"
__global__ void k_sent(bf16_t* __restrict__ out, const int* __restrict__ flags) {
    int i = blockIdx.x * 256 + threadIdx.x;
    if (i >= kNB * kOUT) return;
    float v = -4.1588831f;  // -log(64)
    if (flags[0]) out[i] = f2bf(v);
    else ((float*)out)[i] = v;
}

__global__ void k_setup(unsigned int* __restrict__ deg, float* __restrict__ stats) {
    int i = blockIdx.x * 256 + threadIdx.x;
    if (i < kNN) deg[i] = 1u;   // self loop
    if (i < 384) stats[i] = 0.f;
}

__global__ void k_deg(const int* __restrict__ ei, const int* __restrict__ flags,
                      unsigned int* __restrict__ deg) {
    int e = blockIdx.x * 256 + threadIdx.x;
    if (e >= kNE) return;
    int d = flags[1] ? ei[2 * (kNE + e)] : ei[kNE + e];
    atomicAdd(&deg[d], 1u);
}

__global__ void k_dinv(const unsigned int* __restrict__ deg, float* __restrict__ dinv) {
    int i = blockIdx.x * 256 + threadIdx.x;
    if (i < kNN) dinv[i] = rsqrtf((float)deg[i]);
}

// H1[n,c] = sum_k A[n,k] * W1[k,c]   (N=128, K=256), H1 bf16
__global__ void k_lin1(const void* __restrict__ A, const void* __restrict__ W,
                       bf16_t* __restrict__ H, const int* __restrict__ flags) {
    __shared__ float As[2][256];
    int tid = threadIdx.x;
    int isbf = flags[0];
    int n0 = blockIdx.x * 2;
    for (int j = tid; j < 512; j += 256) {
        int r = j >> 8, k = j & 255;
        int n = n0 + r;
        float v = 0.f;
        if (n < kNN) {
            if (isbf) v = bf2f(((const bf16_t*)A)[(size_t)n * kFEAT + k]);
            else      v = ((const float*)A)[(size_t)n * kFEAT + k];
        }
        As[r][k] = v;
    }
    __syncthreads();
    int r = tid >> 7, c = tid & 127;
    int n = n0 + r;
    if (n >= kNN) return;
    float acc = 0.f;
    if (isbf) {
        const bf16_t* Wb = (const bf16_t*)W;
        for (int k = 0; k < kFEAT; k++) acc += As[r][k] * bf2f(Wb[k * kHID + c]);
    } else {
        const float* Wf = (const float*)W;
        for (int k = 0; k < kFEAT; k++) acc += As[r][k] * Wf[k * kHID + c];
    }
    H[(size_t)n * kHID + c] = f2bf(acc);
}

// A1[n,c] = dinv[n]^2 * H[n,c] + bias[c]
__global__ void k_self1(const bf16_t* __restrict__ H, const float* __restrict__ dinv,
                        const void* __restrict__ bias, const int* __restrict__ flags,
                        float* __restrict__ A1) {
    size_t i = (size_t)blockIdx.x * 256 + threadIdx.x;
    if (i >= (size_t)kNN * kHID) return;
    int n = (int)(i >> 7), c = (int)(i & 127);
    float dn = dinv[n];
    float b = flags[0] ? bf2f(((const bf16_t*)bias)[c]) : ((const float*)bias)[c];
    A1[i] = dn * dn * bf2f(H[i]) + b;
}

// edge scatter: A1[d,c] += dinv[s]*dinv[d]*H[s,c]   (32 threads/edge, 4 ch each)
__global__ void k_scat1(const bf16_t* __restrict__ H, const int* __restrict__ ei,
                        const int* __restrict__ flags, const float* __restrict__ dinv,
                        float* __restrict__ A1) {
    int gid = blockIdx.x * 256 + threadIdx.x;
    int e = gid >> 5;
    int c0 = (gid & 31) * 4;
    if (e >= kNE) return;
    int s, d;
    if (flags[1]) { s = ei[2 * e]; d = ei[2 * (kNE + e)]; }
    else          { s = ei[e];     d = ei[kNE + e]; }
    float w = dinv[s] * dinv[d];
    ushort4 u = *(const ushort4*)(H + (size_t)s * kHID + c0);
    float* p = A1 + (size_t)d * kHID + c0;
    atomicAdd(p + 0, w * bf2f(u.x));
    atomicAdd(p + 1, w * bf2f(u.y));
    atomicAdd(p + 2, w * bf2f(u.z));
    atomicAdd(p + 3, w * bf2f(u.w));
}

__global__ void k_stat1(const float* __restrict__ A1, float* __restrict__ stats) {
    int c = threadIdx.x & 127;
    int r0 = threadIdx.x >> 7;             // 0..1
    int chunk = (kNN + gridDim.x - 1) / gridDim.x;
    int nbeg = blockIdx.x * chunk;
    int nend = nbeg + chunk; if (nend > kNN) nend = kNN;
    float s0 = 0.f, s1 = 0.f;
    for (int n = nbeg + r0; n < nend; n += 2) {
        float v = A1[(size_t)n * kHID + c];
        s0 += v; s1 += v * v;
    }
    atomicAdd(&stats[c], s0);
    atomicAdd(&stats[kHID + c], s1);
}

__global__ void k_bnrelu1(const float* __restrict__ A1, const float* __restrict__ stats,
                          const void* __restrict__ gamma, const void* __restrict__ beta,
                          const int* __restrict__ flags, bf16_t* __restrict__ X1) {
    size_t i = (size_t)blockIdx.x * 256 + threadIdx.x;
    if (i >= (size_t)kNN * kHID) return;
    int c = (int)(i & 127);
    float mu = stats[c] * (1.f / kNN);
    float var = stats[kHID + c] * (1.f / kNN) - mu * mu;
    float g, b;
    if (flags[0]) { g = bf2f(((const bf16_t*)gamma)[c]); b = bf2f(((const bf16_t*)beta)[c]); }
    else          { g = ((const float*)gamma)[c];        b = ((const float*)beta)[c]; }
    float v = (A1[i] - mu) * rsqrtf(var + kEPS) * g + b;
    X1[i] = f2bf(v > 0.f ? v : 0.f);
}

// H2[n,c] = sum_k X1[n,k] * W2[k,c]   (N=64, K=128), H2 bf16
__global__ void k_lin2(const bf16_t* __restrict__ A, const void* __restrict__ W,
                       bf16_t* __restrict__ H, const int* __restrict__ flags) {
    __shared__ float As[4][128];
    int tid = threadIdx.x;
    int isbf = flags[0];
    int n0 = blockIdx.x * 4;
    for (int j = tid; j < 512; j += 256) {
        int r = j >> 7, k = j & 127;
        int n = n0 + r;
        As[r][k] = (n < kNN) ? bf2f(A[(size_t)n * kHID + k]) : 0.f;
    }
    __syncthreads();
    int r = tid >> 6, c = tid & 63;
    int n = n0 + r;
    if (n >= kNN) return;
    float acc = 0.f;
    if (isbf) {
        const bf16_t* Wb = (const bf16_t*)W;
        for (int k = 0; k < kHID; k++) acc += As[r][k] * bf2f(Wb[k * kOUT + c]);
    } else {
        const float* Wf = (const float*)W;
        for (int k = 0; k < kHID; k++) acc += As[r][k] * Wf[k * kOUT + c];
    }
    H[(size_t)n * kOUT + c] = f2bf(acc);
}

__global__ void k_self2(const bf16_t* __restrict__ H, const float* __restrict__ dinv,
                        const void* __restrict__ bias, const int* __restrict__ flags,
                        float* __restrict__ A2) {
    size_t i = (size_t)blockIdx.x * 256 + threadIdx.x;
    if (i >= (size_t)kNN * kOUT) return;
    int n = (int)(i >> 6), c = (int)(i & 63);
    float dn = dinv[n];
    float b = flags[0] ? bf2f(((const bf16_t*)bias)[c]) : ((const float*)bias)[c];
    A2[i] = dn * dn * bf2f(H[i]) + b;
}

__global__ void k_scat2(const bf16_t* __restrict__ H, const int* __restrict__ ei,
                        const int* __restrict__ flags, const float* __restrict__ dinv,
                        float* __restrict__ A2) {
    int gid = blockIdx.x * 256 + threadIdx.x;
    int e = gid >> 4;
    int c0 = (gid & 15) * 4;
    if (e >= kNE) return;
    int s, d;
    if (flags[1]) { s = ei[2 * e]; d = ei[2 * (kNE + e)]; }
    else          { s = ei[e];     d = ei[kNE + e]; }
    float w = dinv[s] * dinv[d];
    ushort4 u = *(const ushort4*)(H + (size_t)s * kOUT + c0);
    float* p = A2 + (size_t)d * kOUT + c0;
    atomicAdd(p + 0, w * bf2f(u.x));
    atomicAdd(p + 1, w * bf2f(u.y));
    atomicAdd(p + 2, w * bf2f(u.z));
    atomicAdd(p + 3, w * bf2f(u.w));
}

__global__ void k_stat2(const float* __restrict__ A2, float* __restrict__ stats) {
    int c = threadIdx.x & 63;
    int r0 = threadIdx.x >> 6;             // 0..3
    int chunk = (kNN + gridDim.x - 1) / gridDim.x;
    int nbeg = blockIdx.x * chunk;
    int nend = nbeg + chunk; if (nend > kNN) nend = kNN;
    float s0 = 0.f, s1 = 0.f;
    for (int n = nbeg + r0; n < nend; n += 4) {
        float v = A2[(size_t)n * kOUT + c];
        s0 += v; s1 += v * v;
    }
    atomicAdd(&stats[256 + c], s0);
    atomicAdd(&stats[320 + c], s1);
}

__global__ void k_out(const float* __restrict__ A2, const float* __restrict__ stats,
                      const int* __restrict__ batch, const void* __restrict__ gamma,
                      const void* __restrict__ beta, const int* __restrict__ flags,
                      bf16_t* __restrict__ out) {
    int wid = threadIdx.x >> 6;
    int lane = threadIdx.x & 63;
    int i = blockIdx.x * 4 + wid;
    if (i >= kNB) return;
    int n = batch[i];
    int c = lane;
    float mu = stats[256 + c] * (1.f / kNN);
    float var = stats[320 + c] * (1.f / kNN) - mu * mu;
    float g, b;
    if (flags[0]) { g = bf2f(((const bf16_t*)gamma)[c]); b = bf2f(((const bf16_t*)beta)[c]); }
    else          { g = ((const float*)gamma)[c];        b = ((const float*)beta)[c]; }
    float v = (A2[(size_t)n * kOUT + c] - mu) * rsqrtf(var + kEPS) * g + b;
    v = v > 0.f ? v : 0.f;
    float m = v;
    for (int o = 32; o; o >>= 1) m = fmaxf(m, __shfl_xor(m, o));
    float ex = expf(v - m);
    float s = ex;
    for (int o = 32; o; o >>= 1) s += __shfl_xor(s, o);
    float r = v - m - logf(s);
    if (flags[0]) out[(size_t)i * kOUT + c] = f2bf(r);
    else ((float*)out)[(size_t)i * kOUT + c] = r;
}

static inline size_t align_up(size_t x, size_t a) { return (x + a - 1) & ~(a - 1); }

extern "C" void kernel_launch(void* const* d_in, const int* in_sizes, int n_in,
                              void* d_out, int out_size, void* d_ws, size_t ws_size,
                              hipStream_t stream) {
    (void)in_sizes; (void)n_in; (void)out_size; (void)ws_size;
    const void* feat = d_in[0];
    const int* ei    = (const int*)d_in[1];
    const int* batch = (const int*)d_in[2];
    const void* W1   = d_in[3];
    const void* b1   = d_in[4];
    const void* g1   = d_in[5];
    const void* be1  = d_in[6];
    const void* W2   = d_in[7];
    const void* b2   = d_in[8];
    const void* g2   = d_in[9];
    const void* be2  = d_in[10];

    char* ws = (char*)d_ws;
    size_t o = 0;
    int*          flags = (int*)(ws + o);          o = align_up(o + 32, 256);
    unsigned int* deg   = (unsigned int*)(ws + o); o = align_up(o + (size_t)kNN * 4, 256);
    float*        dinv  = (float*)(ws + o);        o = align_up(o + (size_t)kNN * 4, 256);
    float*        stats = (float*)(ws + o);        o = align_up(o + 384 * 4, 256);
    bf16_t*       h1    = (bf16_t*)(ws + o);       o = align_up(o + (size_t)kNN * kHID * 2, 256);
    float*        a1    = (float*)(ws + o);        o = align_up(o + (size_t)kNN * kHID * 4, 256);
    bf16_t*       x1 = h1;                           // reuse after scatter1 done
    bf16_t*       h2 = (bf16_t*)a1;                  // reuse after bnrelu1 done
    float*        a2 = (float*)((char*)a1 + 16u * 1024u * 1024u);  // 16MB > 12.8MB h2

    bf16_t* outp = (bf16_t*)d_out;

    k_probe<<<1, 64, 0, stream>>>((const uint32_t*)feat, (const uint32_t*)ei, flags);
    k_sent <<<(kNB * kOUT + 255) / 256, 256, 0, stream>>>(outp, flags);
    k_setup<<<(kNN + 255) / 256, 256, 0, stream>>>(deg, stats);
    k_deg  <<<(kNE + 255) / 256, 256, 0, stream>>>(ei, flags, deg);
    k_dinv <<<(kNN + 255) / 256, 256, 0, stream>>>(deg, dinv);

    // layer 1
    k_lin1   <<<(kNN + 1) / 2, 256, 0, stream>>>(feat, W1, h1, flags);
    k_self1  <<<(kNN * kHID + 255) / 256, 256, 0, stream>>>(h1, dinv, b1, flags, a1);
    k_scat1  <<<(kNE * 32) / 256, 256, 0, stream>>>(h1, ei, flags, dinv, a1);
    k_stat1  <<<256, 256, 0, stream>>>(a1, stats);
    k_bnrelu1<<<(kNN * kHID + 255) / 256, 256, 0, stream>>>(a1, stats, g1, be1, flags, x1);

    // layer 2
    k_lin2 <<<(kNN + 3) / 4, 256, 0, stream>>>(x1, W2, h2, flags);
    k_self2<<<(kNN * kOUT + 255) / 256, 256, 0, stream>>>(h2, dinv, b2, flags, a2);
    k_scat2<<<(kNE * 16) / 256, 256, 0, stream>>>(h2, ei, flags, dinv, a2);
    k_stat2<<<256, 256, 0, stream>>>(a2, stats);

    // gather + BN2 + relu + log_softmax
    k_out<<<(kNB + 3) / 4, 256, 0, stream>>>(a2, stats, batch, g2, be2, flags, outp);
}

// Round 4
// 928.737 us; speedup vs baseline: 5.3319x; 5.3319x over previous
//
#include <hip/hip_runtime.h>
#include <stdint.h>

typedef unsigned short bf16_t;

constexpr int kNN   = 100000;
constexpr int kNE   = 1600000;
constexpr int kFEAT = 256;
constexpr int kHID  = 128;
constexpr int kOUT  = 64;
constexpr int kNB   = 10000;
constexpr float kEPS = 1e-5f;

__device__ __forceinline__ float bf2f(bf16_t u) {
    union { uint32_t i; float f; } v; v.i = ((uint32_t)u) << 16; return v.f;
}
__device__ __forceinline__ bf16_t f2bf(float f) {
    uint32_t u = __float_as_uint(f);
    uint32_t r = (u + 0x7FFFu + ((u >> 16) & 1u)) >> 16;
    return (bf16_t)r;
}

// flags[0]: 1 if float tensors are bf16, 0 if fp32.  flags[1]: 1 if edge_index int64.
__global__ void k_probe(const uint32_t* __restrict__ feat, const uint32_t* __restrict__ ei,
                        int* __restrict__ flags) {
    if (blockIdx.x == 0 && threadIdx.x == 0) {
        int good = 0;
        for (int j = 0; j < 256; j++) {
            uint32_t u = feat[j];
            uint32_t e = (u >> 7) & 0xFFu;
            if (e >= 100u && e <= 132u) good++;
        }
        flags[0] = (good > 128) ? 1 : 0;
        int zeros = 0;
        for (int j = 0; j < 128; j++) {
            if (ei[2 * j + 1] == 0u) zeros++;
        }
        flags[1] = (zeros > 64) ? 1 : 0;
    }
}

__global__ void k_setup(unsigned int* __restrict__ deg, float* __restrict__ stats,
                        unsigned int* __restrict__ gtotal) {
    int i = blockIdx.x * 256 + threadIdx.x;
    if (i < kNN) deg[i] = 1u;   // self loop
    if (i < 384) stats[i] = 0.f;
    if (i == 0) gtotal[0] = 0u;
}

__global__ void k_deg(const int* __restrict__ ei, const int* __restrict__ flags,
                      unsigned int* __restrict__ deg) {
    int e = blockIdx.x * 256 + threadIdx.x;
    if (e >= kNE) return;
    int d = flags[1] ? ei[2 * (kNE + e)] : ei[kNE + e];
    atomicAdd(&deg[d], 1u);
}

__global__ void k_dinv(const unsigned int* __restrict__ deg, float* __restrict__ dinv) {
    int i = blockIdx.x * 256 + threadIdx.x;
    if (i < kNN) dinv[i] = rsqrtf((float)deg[i]);
}

// per-block scan + one atomic -> CSR slice base per node (order irrelevant)
__global__ void k_assign(const unsigned int* __restrict__ deg, unsigned int* __restrict__ cursor,
                         unsigned int* __restrict__ gtotal) {
    __shared__ unsigned int ss[256];
    __shared__ unsigned int sbase;
    int t = threadIdx.x;
    int i = blockIdx.x * 256 + t;
    unsigned int v = (i < kNN) ? (deg[i] - 1u) : 0u;
    ss[t] = v;
    __syncthreads();
    for (int off = 1; off < 256; off <<= 1) {
        unsigned int x = (t >= off) ? ss[t - off] : 0u;
        __syncthreads();
        ss[t] += x;
        __syncthreads();
    }
    if (t == 255) sbase = atomicAdd(gtotal, ss[255]);
    __syncthreads();
    if (i < kNN) cursor[i] = sbase + ss[t] - v;
}

__global__ void k_bucket(const int* __restrict__ ei, const int* __restrict__ flags,
                         unsigned int* __restrict__ cursor, int* __restrict__ sorted) {
    int e = blockIdx.x * 256 + threadIdx.x;
    if (e >= kNE) return;
    int s, d;
    if (flags[1]) { s = ei[2 * e]; d = ei[2 * (kNE + e)]; }
    else          { s = ei[e];     d = ei[kNE + e]; }
    unsigned int p = atomicAdd(&cursor[d], 1u);
    sorted[p] = s;
}

// H[n,c] = dinv[n] * sum_k A[n,k]*W1[k,c]   (M=100000,K=256,N=128), H bf16
__global__ void k_gemm1(const void* __restrict__ A, const void* __restrict__ W,
                        const float* __restrict__ dinv, bf16_t* __restrict__ H,
                        const int* __restrict__ flags) {
    __shared__ float As[64][65];
    __shared__ float Bs[64][128];
    int isbf = flags[0];
    int tid = threadIdx.x;
    int tx = tid & 15, ty = tid >> 4;
    int row0 = blockIdx.x * 64;
    float acc[4][8];
    for (int r = 0; r < 4; r++)
        for (int j = 0; j < 8; j++) acc[r][j] = 0.f;

    for (int k0 = 0; k0 < kFEAT; k0 += 64) {
        {   // stage A transposed
            int slot = tid & 15;
            int rb = tid >> 4;
            for (int p = 0; p < 4; p++) {
                int r = rb + p * 16;
                int grow = row0 + r;
                float x0 = 0.f, x1 = 0.f, x2 = 0.f, x3 = 0.f;
                if (grow < kNN) {
                    size_t idx = (size_t)grow * kFEAT + k0 + slot * 4;
                    if (isbf) {
                        ushort4 u = *(const ushort4*)((const bf16_t*)A + idx);
                        x0 = bf2f(u.x); x1 = bf2f(u.y); x2 = bf2f(u.z); x3 = bf2f(u.w);
                    } else {
                        float4 f = *(const float4*)((const float*)A + idx);
                        x0 = f.x; x1 = f.y; x2 = f.z; x3 = f.w;
                    }
                }
                As[slot * 4 + 0][r] = x0;
                As[slot * 4 + 1][r] = x1;
                As[slot * 4 + 2][r] = x2;
                As[slot * 4 + 3][r] = x3;
            }
        }
        {   // stage B (W1 slab 64x128)
            int bslot = tid & 31;
            int brb = tid >> 5;
            for (int p = 0; p < 8; p++) {
                int r = brb + p * 8;
                size_t idx = (size_t)(k0 + r) * kHID + bslot * 4;
                float4 f;
                if (isbf) {
                    ushort4 u = *(const ushort4*)((const bf16_t*)W + idx);
                    f.x = bf2f(u.x); f.y = bf2f(u.y); f.z = bf2f(u.z); f.w = bf2f(u.w);
                } else {
                    f = *(const float4*)((const float*)W + idx);
                }
                *((float4*)&Bs[r][bslot * 4]) = f;
            }
        }
        __syncthreads();
        for (int k = 0; k < 64; k++) {
            float a0 = As[k][ty * 4 + 0];
            float a1 = As[k][ty * 4 + 1];
            float a2 = As[k][ty * 4 + 2];
            float a3 = As[k][ty * 4 + 3];
            float b[8];
            for (int j = 0; j < 8; j += 4) {
                float4 bv = *((const float4*)&Bs[k][tx * 8 + j]);
                b[j] = bv.x; b[j + 1] = bv.y; b[j + 2] = bv.z; b[j + 3] = bv.w;
            }
            for (int j = 0; j < 8; j++) {
                acc[0][j] += a0 * b[j];
                acc[1][j] += a1 * b[j];
                acc[2][j] += a2 * b[j];
                acc[3][j] += a3 * b[j];
            }
        }
        __syncthreads();
    }
    for (int r = 0; r < 4; r++) {
        int grow = row0 + ty * 4 + r;
        if (grow < kNN) {
            float dn = dinv[grow];
            uint4 w;
            w.x = (uint32_t)f2bf(acc[r][0] * dn) | ((uint32_t)f2bf(acc[r][1] * dn) << 16);
            w.y = (uint32_t)f2bf(acc[r][2] * dn) | ((uint32_t)f2bf(acc[r][3] * dn) << 16);
            w.z = (uint32_t)f2bf(acc[r][4] * dn) | ((uint32_t)f2bf(acc[r][5] * dn) << 16);
            w.w = (uint32_t)f2bf(acc[r][6] * dn) | ((uint32_t)f2bf(acc[r][7] * dn) << 16);
            *(uint4*)(H + (size_t)grow * kHID + tx * 8) = w;
        }
    }
}

// A1[n,c] = dinv[n]*(sum_edges Hs[s,c] + Hs[n,c]) + b1[c]; Hs pre-scaled. C=128, 2ch/thread
__global__ void k_agg1(const bf16_t* __restrict__ H, const int* __restrict__ sorted,
                       const unsigned int* __restrict__ cursor, const unsigned int* __restrict__ deg,
                       const float* __restrict__ dinv, const void* __restrict__ bias,
                       const int* __restrict__ flags, float* __restrict__ Out) {
    int t = threadIdx.x;
    int local = t >> 6;
    int lane = t & 63;
    int c0 = lane * 2;
    int n = blockIdx.x * 4 + local;
    if (n >= kNN) return;
    float dn = dinv[n];
    uint32_t hu = *(const uint32_t*)(H + (size_t)n * kHID + c0);
    float acc0 = bf2f((bf16_t)(hu & 0xFFFFu));
    float acc1 = bf2f((bf16_t)(hu >> 16));
    unsigned int e1 = cursor[n];
    unsigned int e0 = e1 - (deg[n] - 1u);
    for (unsigned int e = e0; e < e1; e++) {
        int s = sorted[e];
        uint32_t u = *(const uint32_t*)(H + (size_t)s * kHID + c0);
        acc0 += bf2f((bf16_t)(u & 0xFFFFu));
        acc1 += bf2f((bf16_t)(u >> 16));
    }
    float b0, b1v;
    if (flags[0]) { b0 = bf2f(((const bf16_t*)bias)[c0]); b1v = bf2f(((const bf16_t*)bias)[c0 + 1]); }
    else          { b0 = ((const float*)bias)[c0];        b1v = ((const float*)bias)[c0 + 1]; }
    float2 o; o.x = acc0 * dn + b0; o.y = acc1 * dn + b1v;
    *(float2*)(Out + (size_t)n * kHID + c0) = o;
}

__global__ void k_stat1(const float* __restrict__ A1, float* __restrict__ stats) {
    int c = threadIdx.x & 127;
    int r0 = threadIdx.x >> 7;
    int chunk = (kNN + gridDim.x - 1) / gridDim.x;
    int nbeg = blockIdx.x * chunk;
    int nend = nbeg + chunk; if (nend > kNN) nend = kNN;
    float s0 = 0.f, s1 = 0.f;
    for (int n = nbeg + r0; n < nend; n += 2) {
        float v = A1[(size_t)n * kHID + c];
        s0 += v; s1 += v * v;
    }
    atomicAdd(&stats[c], s0);
    atomicAdd(&stats[kHID + c], s1);
}

__global__ void k_bnrelu1(const float* __restrict__ A1, const float* __restrict__ stats,
                          const void* __restrict__ gamma, const void* __restrict__ beta,
                          const int* __restrict__ flags, bf16_t* __restrict__ X1) {
    size_t i = (size_t)blockIdx.x * 256 + threadIdx.x;
    if (i >= (size_t)kNN * kHID) return;
    int c = (int)(i & 127);
    float mu = stats[c] * (1.f / kNN);
    float var = stats[kHID + c] * (1.f / kNN) - mu * mu;
    float g, b;
    if (flags[0]) { g = bf2f(((const bf16_t*)gamma)[c]); b = bf2f(((const bf16_t*)beta)[c]); }
    else          { g = ((const float*)gamma)[c];        b = ((const float*)beta)[c]; }
    float v = (A1[i] - mu) * rsqrtf(var + kEPS) * g + b;
    X1[i] = f2bf(v > 0.f ? v : 0.f);
}

// H2[n,c] = dinv[n] * sum_k X1[n,k]*W2[k,c]   (K=128,N=64), bf16 out
__global__ void k_gemm2(const bf16_t* __restrict__ A, const void* __restrict__ W,
                        const float* __restrict__ dinv, bf16_t* __restrict__ H,
                        const int* __restrict__ flags) {
    __shared__ float As[64][65];
    __shared__ float Bs[64][64];
    int isbf = flags[0];
    int tid = threadIdx.x;
    int tx = tid & 15, ty = tid >> 4;
    int row0 = blockIdx.x * 64;
    float acc[4][4];
    for (int r = 0; r < 4; r++)
        for (int j = 0; j < 4; j++) acc[r][j] = 0.f;

    for (int k0 = 0; k0 < kHID; k0 += 64) {
        {
            int slot = tid & 15;
            int rb = tid >> 4;
            for (int p = 0; p < 4; p++) {
                int r = rb + p * 16;
                int grow = row0 + r;
                float x0 = 0.f, x1 = 0.f, x2 = 0.f, x3 = 0.f;
                if (grow < kNN) {
                    ushort4 u = *(const ushort4*)(A + (size_t)grow * kHID + k0 + slot * 4);
                    x0 = bf2f(u.x); x1 = bf2f(u.y); x2 = bf2f(u.z); x3 = bf2f(u.w);
                }
                As[slot * 4 + 0][r] = x0;
                As[slot * 4 + 1][r] = x1;
                As[slot * 4 + 2][r] = x2;
                As[slot * 4 + 3][r] = x3;
            }
        }
        {
            int bslot = tid & 15;
            int brb = tid >> 4;
            for (int p = 0; p < 4; p++) {
                int r = brb + p * 16;
                size_t idx = (size_t)(k0 + r) * kOUT + bslot * 4;
                float4 f;
                if (isbf) {
                    ushort4 u = *(const ushort4*)((const bf16_t*)W + idx);
                    f.x = bf2f(u.x); f.y = bf2f(u.y); f.z = bf2f(u.z); f.w = bf2f(u.w);
                } else {
                    f = *(const float4*)((const float*)W + idx);
                }
                *((float4*)&Bs[r][bslot * 4]) = f;
            }
        }
        __syncthreads();
        for (int k = 0; k < 64; k++) {
            float a0 = As[k][ty * 4 + 0];
            float a1 = As[k][ty * 4 + 1];
            float a2 = As[k][ty * 4 + 2];
            float a3 = As[k][ty * 4 + 3];
            float4 bv = *((const float4*)&Bs[k][tx * 4]);
            float b[4] = {bv.x, bv.y, bv.z, bv.w};
            for (int j = 0; j < 4; j++) {
                acc[0][j] += a0 * b[j];
                acc[1][j] += a1 * b[j];
                acc[2][j] += a2 * b[j];
                acc[3][j] += a3 * b[j];
            }
        }
        __syncthreads();
    }
    for (int r = 0; r < 4; r++) {
        int grow = row0 + ty * 4 + r;
        if (grow < kNN) {
            float dn = dinv[grow];
            uint2 w;
            w.x = (uint32_t)f2bf(acc[r][0] * dn) | ((uint32_t)f2bf(acc[r][1] * dn) << 16);
            w.y = (uint32_t)f2bf(acc[r][2] * dn) | ((uint32_t)f2bf(acc[r][3] * dn) << 16);
            *(uint2*)(H + (size_t)grow * kOUT + tx * 4) = w;
        }
    }
}

// C=64, 1 ch/thread, 4 nodes/block
__global__ void k_agg2(const bf16_t* __restrict__ H, const int* __restrict__ sorted,
                       const unsigned int* __restrict__ cursor, const unsigned int* __restrict__ deg,
                       const float* __restrict__ dinv, const void* __restrict__ bias,
                       const int* __restrict__ flags, float* __restrict__ Out) {
    int t = threadIdx.x;
    int local = t >> 6;
    int c = t & 63;
    int n = blockIdx.x * 4 + local;
    if (n >= kNN) return;
    float dn = dinv[n];
    float acc = bf2f(H[(size_t)n * kOUT + c]);
    unsigned int e1 = cursor[n];
    unsigned int e0 = e1 - (deg[n] - 1u);
    for (unsigned int e = e0; e < e1; e++) {
        int s = sorted[e];
        acc += bf2f(H[(size_t)s * kOUT + c]);
    }
    float b = flags[0] ? bf2f(((const bf16_t*)bias)[c]) : ((const float*)bias)[c];
    Out[(size_t)n * kOUT + c] = acc * dn + b;
}

__global__ void k_stat2(const float* __restrict__ A2, float* __restrict__ stats) {
    int c = threadIdx.x & 63;
    int r0 = threadIdx.x >> 6;
    int chunk = (kNN + gridDim.x - 1) / gridDim.x;
    int nbeg = blockIdx.x * chunk;
    int nend = nbeg + chunk; if (nend > kNN) nend = kNN;
    float s0 = 0.f, s1 = 0.f;
    for (int n = nbeg + r0; n < nend; n += 4) {
        float v = A2[(size_t)n * kOUT + c];
        s0 += v; s1 += v * v;
    }
    atomicAdd(&stats[256 + c], s0);
    atomicAdd(&stats[320 + c], s1);
}

__global__ void k_out(const float* __restrict__ A2, const float* __restrict__ stats,
                      const int* __restrict__ batch, const void* __restrict__ gamma,
                      const void* __restrict__ beta, const int* __restrict__ flags,
                      bf16_t* __restrict__ out) {
    int wid = threadIdx.x >> 6;
    int lane = threadIdx.x & 63;
    int i = blockIdx.x * 4 + wid;
    if (i >= kNB) return;
    int n = batch[i];
    int c = lane;
    float mu = stats[256 + c] * (1.f / kNN);
    float var = stats[320 + c] * (1.f / kNN) - mu * mu;
    float g, b;
    if (flags[0]) { g = bf2f(((const bf16_t*)gamma)[c]); b = bf2f(((const bf16_t*)beta)[c]); }
    else          { g = ((const float*)gamma)[c];        b = ((const float*)beta)[c]; }
    float v = (A2[(size_t)n * kOUT + c] - mu) * rsqrtf(var + kEPS) * g + b;
    v = v > 0.f ? v : 0.f;
    float m = v;
    for (int o = 32; o; o >>= 1) m = fmaxf(m, __shfl_xor(m, o));
    float ex = expf(v - m);
    float s = ex;
    for (int o = 32; o; o >>= 1) s += __shfl_xor(s, o);
    float r = v - m - logf(s);
    if (flags[0]) out[(size_t)i * kOUT + c] = f2bf(r);
    else ((float*)out)[(size_t)i * kOUT + c] = r;
}

static inline size_t align_up(size_t x, size_t a) { return (x + a - 1) & ~(a - 1); }

extern "C" void kernel_launch(void* const* d_in, const int* in_sizes, int n_in,
                              void* d_out, int out_size, void* d_ws, size_t ws_size,
                              hipStream_t stream) {
    (void)in_sizes; (void)n_in; (void)out_size; (void)ws_size;
    const void* feat = d_in[0];
    const int* ei    = (const int*)d_in[1];
    const int* batch = (const int*)d_in[2];
    const void* W1   = d_in[3];
    const void* b1   = d_in[4];
    const void* g1   = d_in[5];
    const void* be1  = d_in[6];
    const void* W2   = d_in[7];
    const void* b2   = d_in[8];
    const void* g2   = d_in[9];
    const void* be2  = d_in[10];

    char* ws = (char*)d_ws;
    size_t o = 0;
    int*          flags  = (int*)(ws + o);          o = align_up(o + 32, 256);
    unsigned int* gtotal = (unsigned int*)(ws + o); o = align_up(o + 16, 256);
    unsigned int* deg    = (unsigned int*)(ws + o); o = align_up(o + (size_t)kNN * 4, 256);
    float*        dinv   = (float*)(ws + o);        o = align_up(o + (size_t)kNN * 4, 256);
    unsigned int* cursor = (unsigned int*)(ws + o); o = align_up(o + (size_t)kNN * 4, 256);
    float*        stats  = (float*)(ws + o);        o = align_up(o + 384 * 4, 256);
    int*          sorted = (int*)(ws + o);          o = align_up(o + (size_t)kNE * 4, 256);
    bf16_t*       h1     = (bf16_t*)(ws + o);       o = align_up(o + (size_t)kNN * kHID * 2, 256);
    float*        a1     = (float*)(ws + o);        o = align_up(o + (size_t)kNN * kHID * 4, 256);
    bf16_t*       x1 = h1;                            // h1 dead after agg1
    bf16_t*       h2 = (bf16_t*)a1;                   // a1 dead after bnrelu1
    float*        a2 = (float*)((char*)a1 + 16u * 1024u * 1024u);  // 16MB > 12.8MB h2

    bf16_t* outp = (bf16_t*)d_out;

    // graph build
    k_probe <<<1, 64, 0, stream>>>((const uint32_t*)feat, (const uint32_t*)ei, flags);
    k_setup <<<(kNN + 255) / 256, 256, 0, stream>>>(deg, stats, gtotal);
    k_deg   <<<(kNE + 255) / 256, 256, 0, stream>>>(ei, flags, deg);
    k_dinv  <<<(kNN + 255) / 256, 256, 0, stream>>>(deg, dinv);
    k_assign<<<(kNN + 255) / 256, 256, 0, stream>>>(deg, cursor, gtotal);
    k_bucket<<<(kNE + 255) / 256, 256, 0, stream>>>(ei, flags, cursor, sorted);

    // layer 1
    k_gemm1  <<<(kNN + 63) / 64, 256, 0, stream>>>(feat, W1, dinv, h1, flags);
    k_agg1   <<<(kNN + 3) / 4, 256, 0, stream>>>(h1, sorted, cursor, deg, dinv, b1, flags, a1);
    k_stat1  <<<256, 256, 0, stream>>>(a1, stats);
    k_bnrelu1<<<(kNN * kHID + 255) / 256, 256, 0, stream>>>(a1, stats, g1, be1, flags, x1);

    // layer 2
    k_gemm2<<<(kNN + 63) / 64, 256, 0, stream>>>(x1, W2, dinv, h2, flags);
    k_agg2 <<<(kNN + 3) / 4, 256, 0, stream>>>(h2, sorted, cursor, deg, dinv, b2, flags, a2);
    k_stat2<<<256, 256, 0, stream>>>(a2, stats);

    // gather + BN2 + relu + log_softmax
    k_out<<<(kNB + 3) / 4, 256, 0, stream>>>(a2, stats, batch, g2, be2, flags, outp);
}

// Round 7
// 757.479 us; speedup vs baseline: 6.5374x; 1.2261x over previous
//
#include <hip/hip_runtime.h>
#include <stdint.h>

typedef unsigned short bf16_t;

constexpr int kNN   = 100000;
constexpr int kNE   = 1600000;
constexpr int kFEAT = 256;
constexpr int kHID  = 128;
constexpr int kOUT  = 64;
constexpr int kNB   = 10000;
constexpr float kEPS = 1e-5f;

__device__ __forceinline__ float bf2f(bf16_t u) {
    union { uint32_t i; float f; } v; v.i = ((uint32_t)u) << 16; return v.f;
}
__device__ __forceinline__ bf16_t f2bf(float f) {
    uint32_t u = __float_as_uint(f);
    uint32_t r = (u + 0x7FFFu + ((u >> 16) & 1u)) >> 16;
    return (bf16_t)r;
}
__device__ __forceinline__ float lo16(uint32_t u) {
    union { uint32_t i; float f; } v; v.i = u << 16; return v.f;
}
__device__ __forceinline__ float hi16(uint32_t u) {
    union { uint32_t i; float f; } v; v.i = u & 0xFFFF0000u; return v.f;
}

// flags[0]: 1 if float tensors are bf16, 0 if fp32.  flags[1]: 1 if edge_index int64.
__global__ void k_probe(const uint32_t* __restrict__ feat, const uint32_t* __restrict__ ei,
                        int* __restrict__ flags) {
    if (blockIdx.x == 0 && threadIdx.x == 0) {
        int good = 0;
        for (int j = 0; j < 256; j++) {
            uint32_t u = feat[j];
            uint32_t e = (u >> 7) & 0xFFu;
            if (e >= 100u && e <= 132u) good++;
        }
        flags[0] = (good > 128) ? 1 : 0;
        int zeros = 0;
        for (int j = 0; j < 128; j++) {
            if (ei[2 * j + 1] == 0u) zeros++;
        }
        flags[1] = (zeros > 64) ? 1 : 0;
    }
}

__global__ void k_setup(unsigned int* __restrict__ deg, float* __restrict__ stats,
                        unsigned int* __restrict__ gtotal) {
    int i = blockIdx.x * 256 + threadIdx.x;
    if (i < kNN) deg[i] = 1u;   // self loop
    if (i < 384) stats[i] = 0.f;
    if (i == 0) gtotal[0] = 0u;
}

__global__ void k_deg(const int* __restrict__ ei, const int* __restrict__ flags,
                      unsigned int* __restrict__ deg) {
    int e = blockIdx.x * 256 + threadIdx.x;
    if (e >= kNE) return;
    int d = flags[1] ? ei[2 * (kNE + e)] : ei[kNE + e];
    atomicAdd(&deg[d], 1u);
}

__global__ void k_dinv(const unsigned int* __restrict__ deg, float* __restrict__ dinv) {
    int i = blockIdx.x * 256 + threadIdx.x;
    if (i < kNN) dinv[i] = rsqrtf((float)deg[i]);
}

// per-block scan + one atomic -> CSR slice base per node (order irrelevant)
__global__ void k_assign(const unsigned int* __restrict__ deg, unsigned int* __restrict__ cursor,
                         unsigned int* __restrict__ gtotal) {
    __shared__ unsigned int ss[256];
    __shared__ unsigned int sbase;
    int t = threadIdx.x;
    int i = blockIdx.x * 256 + t;
    unsigned int v = (i < kNN) ? (deg[i] - 1u) : 0u;
    ss[t] = v;
    __syncthreads();
    for (int off = 1; off < 256; off <<= 1) {
        unsigned int x = (t >= off) ? ss[t - off] : 0u;
        __syncthreads();
        ss[t] += x;
        __syncthreads();
    }
    if (t == 255) sbase = atomicAdd(gtotal, ss[255]);
    __syncthreads();
    if (i < kNN) cursor[i] = sbase + ss[t] - v;
}

__global__ void k_bucket(const int* __restrict__ ei, const int* __restrict__ flags,
                         unsigned int* __restrict__ cursor, int* __restrict__ sorted) {
    int e = blockIdx.x * 256 + threadIdx.x;
    if (e >= kNE) return;
    int s, d;
    if (flags[1]) { s = ei[2 * e]; d = ei[2 * (kNE + e)]; }
    else          { s = ei[e];     d = ei[kNE + e]; }
    unsigned int p = atomicAdd(&cursor[d], 1u);
    sorted[p] = s;
}

// H[n,c] = dinv[n] * sum_k A[n,k]*W1[k,c]   (M=100000,K=256,N=128), H bf16
__global__ void k_gemm1(const void* __restrict__ A, const void* __restrict__ W,
                        const float* __restrict__ dinv, bf16_t* __restrict__ H,
                        const int* __restrict__ flags) {
    __shared__ float As[64][65];
    __shared__ float Bs[64][128];
    int isbf = flags[0];
    int tid = threadIdx.x;
    int tx = tid & 15, ty = tid >> 4;
    int row0 = blockIdx.x * 64;
    float acc[4][8];
    for (int r = 0; r < 4; r++)
        for (int j = 0; j < 8; j++) acc[r][j] = 0.f;

    for (int k0 = 0; k0 < kFEAT; k0 += 64) {
        {   // stage A transposed
            int slot = tid & 15;
            int rb = tid >> 4;
            for (int p = 0; p < 4; p++) {
                int r = rb + p * 16;
                int grow = row0 + r;
                float x0 = 0.f, x1 = 0.f, x2 = 0.f, x3 = 0.f;
                if (grow < kNN) {
                    size_t idx = (size_t)grow * kFEAT + k0 + slot * 4;
                    if (isbf) {
                        ushort4 u = *(const ushort4*)((const bf16_t*)A + idx);
                        x0 = bf2f(u.x); x1 = bf2f(u.y); x2 = bf2f(u.z); x3 = bf2f(u.w);
                    } else {
                        float4 f = *(const float4*)((const float*)A + idx);
                        x0 = f.x; x1 = f.y; x2 = f.z; x3 = f.w;
                    }
                }
                As[slot * 4 + 0][r] = x0;
                As[slot * 4 + 1][r] = x1;
                As[slot * 4 + 2][r] = x2;
                As[slot * 4 + 3][r] = x3;
            }
        }
        {   // stage B (W1 slab 64x128)
            int bslot = tid & 31;
            int brb = tid >> 5;
            for (int p = 0; p < 8; p++) {
                int r = brb + p * 8;
                size_t idx = (size_t)(k0 + r) * kHID + bslot * 4;
                float4 f;
                if (isbf) {
                    ushort4 u = *(const ushort4*)((const bf16_t*)W + idx);
                    f.x = bf2f(u.x); f.y = bf2f(u.y); f.z = bf2f(u.z); f.w = bf2f(u.w);
                } else {
                    f = *(const float4*)((const float*)W + idx);
                }
                *((float4*)&Bs[r][bslot * 4]) = f;
            }
        }
        __syncthreads();
        for (int k = 0; k < 64; k++) {
            float a0 = As[k][ty * 4 + 0];
            float a1 = As[k][ty * 4 + 1];
            float a2 = As[k][ty * 4 + 2];
            float a3 = As[k][ty * 4 + 3];
            float b[8];
            for (int j = 0; j < 8; j += 4) {
                float4 bv = *((const float4*)&Bs[k][tx * 8 + j]);
                b[j] = bv.x; b[j + 1] = bv.y; b[j + 2] = bv.z; b[j + 3] = bv.w;
            }
            for (int j = 0; j < 8; j++) {
                acc[0][j] += a0 * b[j];
                acc[1][j] += a1 * b[j];
                acc[2][j] += a2 * b[j];
                acc[3][j] += a3 * b[j];
            }
        }
        __syncthreads();
    }
    for (int r = 0; r < 4; r++) {
        int grow = row0 + ty * 4 + r;
        if (grow < kNN) {
            float dn = dinv[grow];
            uint4 w;
            w.x = (uint32_t)f2bf(acc[r][0] * dn) | ((uint32_t)f2bf(acc[r][1] * dn) << 16);
            w.y = (uint32_t)f2bf(acc[r][2] * dn) | ((uint32_t)f2bf(acc[r][3] * dn) << 16);
            w.z = (uint32_t)f2bf(acc[r][4] * dn) | ((uint32_t)f2bf(acc[r][5] * dn) << 16);
            w.w = (uint32_t)f2bf(acc[r][6] * dn) | ((uint32_t)f2bf(acc[r][7] * dn) << 16);
            *(uint4*)(H + (size_t)grow * kHID + tx * 8) = w;
        }
    }
}

// A1[n,c] = dinv[n]*(sum_edges Hs[s,c] + Hs[n,c]) + b1[c]; 4 nodes/block, 2ch/lane, unroll 4
__global__ void k_agg1(const bf16_t* __restrict__ H, const int* __restrict__ sorted,
                       const unsigned int* __restrict__ cursor, const unsigned int* __restrict__ deg,
                       const float* __restrict__ dinv, const void* __restrict__ bias,
                       const int* __restrict__ flags, float* __restrict__ Out) {
    int t = threadIdx.x;
    int local = t >> 6;
    int lane = t & 63;
    int c0 = lane * 2;
    int n = blockIdx.x * 4 + local;
    if (n >= kNN) return;
    const uint32_t* Hrow = (const uint32_t*)H;   // 2 bf16 ch per word, 64 words/row
    float dn = dinv[n];
    uint32_t hu = Hrow[(size_t)n * 64 + lane];
    float acc0 = lo16(hu), acc1 = hi16(hu);
    unsigned int e1 = cursor[n];
    unsigned int e = e1 - (deg[n] - 1u);
    int cnt = (int)(e1 - e);
    for (; cnt >= 4; cnt -= 4, e += 4) {
        int s0 = sorted[e], s1 = sorted[e + 1], s2 = sorted[e + 2], s3 = sorted[e + 3];
        uint32_t u0 = Hrow[(size_t)s0 * 64 + lane];
        uint32_t u1 = Hrow[(size_t)s1 * 64 + lane];
        uint32_t u2 = Hrow[(size_t)s2 * 64 + lane];
        uint32_t u3 = Hrow[(size_t)s3 * 64 + lane];
        acc0 += lo16(u0) + lo16(u1) + lo16(u2) + lo16(u3);
        acc1 += hi16(u0) + hi16(u1) + hi16(u2) + hi16(u3);
    }
    for (; cnt > 0; cnt--, e++) {
        uint32_t u = Hrow[(size_t)sorted[e] * 64 + lane];
        acc0 += lo16(u);
        acc1 += hi16(u);
    }
    float b0, b1v;
    if (flags[0]) { b0 = bf2f(((const bf16_t*)bias)[c0]); b1v = bf2f(((const bf16_t*)bias)[c0 + 1]); }
    else          { b0 = ((const float*)bias)[c0];        b1v = ((const float*)bias)[c0 + 1]; }
    float2 o; o.x = acc0 * dn + b0; o.y = acc1 * dn + b1v;
    *(float2*)(Out + (size_t)n * kHID + c0) = o;
}

__global__ void k_stat1(const float* __restrict__ A1, float* __restrict__ stats) {
    int c = threadIdx.x & 127;
    int r0 = threadIdx.x >> 7;
    int chunk = (kNN + gridDim.x - 1) / gridDim.x;
    int nbeg = blockIdx.x * chunk;
    int nend = nbeg + chunk; if (nend > kNN) nend = kNN;
    float s0 = 0.f, s1 = 0.f;
    for (int n = nbeg + r0; n < nend; n += 2) {
        float v = A1[(size_t)n * kHID + c];
        s0 += v; s1 += v * v;
    }
    atomicAdd(&stats[c], s0);
    atomicAdd(&stats[kHID + c], s1);
}

__global__ void k_bnrelu1(const float* __restrict__ A1, const float* __restrict__ stats,
                          const void* __restrict__ gamma, const void* __restrict__ beta,
                          const int* __restrict__ flags, bf16_t* __restrict__ X1) {
    size_t i = (size_t)blockIdx.x * 256 + threadIdx.x;
    if (i >= (size_t)kNN * kHID) return;
    int c = (int)(i & 127);
    float mu = stats[c] * (1.f / kNN);
    float var = stats[kHID + c] * (1.f / kNN) - mu * mu;
    float g, b;
    if (flags[0]) { g = bf2f(((const bf16_t*)gamma)[c]); b = bf2f(((const bf16_t*)beta)[c]); }
    else          { g = ((const float*)gamma)[c];        b = ((const float*)beta)[c]; }
    float v = (A1[i] - mu) * rsqrtf(var + kEPS) * g + b;
    X1[i] = f2bf(v > 0.f ? v : 0.f);
}

// H2[n,c] = dinv[n] * sum_k X1[n,k]*W2[k,c]   (K=128,N=64), bf16 out
__global__ void k_gemm2(const bf16_t* __restrict__ A, const void* __restrict__ W,
                        const float* __restrict__ dinv, bf16_t* __restrict__ H,
                        const int* __restrict__ flags) {
    __shared__ float As[64][65];
    __shared__ float Bs[64][64];
    int isbf = flags[0];
    int tid = threadIdx.x;
    int tx = tid & 15, ty = tid >> 4;
    int row0 = blockIdx.x * 64;
    float acc[4][4];
    for (int r = 0; r < 4; r++)
        for (int j = 0; j < 4; j++) acc[r][j] = 0.f;

    for (int k0 = 0; k0 < kHID; k0 += 64) {
        {
            int slot = tid & 15;
            int rb = tid >> 4;
            for (int p = 0; p < 4; p++) {
                int r = rb + p * 16;
                int grow = row0 + r;
                float x0 = 0.f, x1 = 0.f, x2 = 0.f, x3 = 0.f;
                if (grow < kNN) {
                    ushort4 u = *(const ushort4*)(A + (size_t)grow * kHID + k0 + slot * 4);
                    x0 = bf2f(u.x); x1 = bf2f(u.y); x2 = bf2f(u.z); x3 = bf2f(u.w);
                }
                As[slot * 4 + 0][r] = x0;
                As[slot * 4 + 1][r] = x1;
                As[slot * 4 + 2][r] = x2;
                As[slot * 4 + 3][r] = x3;
            }
        }
        {
            int bslot = tid & 15;
            int brb = tid >> 4;
            for (int p = 0; p < 4; p++) {
                int r = brb + p * 16;
                size_t idx = (size_t)(k0 + r) * kOUT + bslot * 4;
                float4 f;
                if (isbf) {
                    ushort4 u = *(const ushort4*)((const bf16_t*)W + idx);
                    f.x = bf2f(u.x); f.y = bf2f(u.y); f.z = bf2f(u.z); f.w = bf2f(u.w);
                } else {
                    f = *(const float4*)((const float*)W + idx);
                }
                *((float4*)&Bs[r][bslot * 4]) = f;
            }
        }
        __syncthreads();
        for (int k = 0; k < 64; k++) {
            float a0 = As[k][ty * 4 + 0];
            float a1 = As[k][ty * 4 + 1];
            float a2 = As[k][ty * 4 + 2];
            float a3 = As[k][ty * 4 + 3];
            float4 bv = *((const float4*)&Bs[k][tx * 4]);
            float b[4] = {bv.x, bv.y, bv.z, bv.w};
            for (int j = 0; j < 4; j++) {
                acc[0][j] += a0 * b[j];
                acc[1][j] += a1 * b[j];
                acc[2][j] += a2 * b[j];
                acc[3][j] += a3 * b[j];
            }
        }
        __syncthreads();
    }
    for (int r = 0; r < 4; r++) {
        int grow = row0 + ty * 4 + r;
        if (grow < kNN) {
            float dn = dinv[grow];
            uint2 w;
            w.x = (uint32_t)f2bf(acc[r][0] * dn) | ((uint32_t)f2bf(acc[r][1] * dn) << 16);
            w.y = (uint32_t)f2bf(acc[r][2] * dn) | ((uint32_t)f2bf(acc[r][3] * dn) << 16);
            *(uint2*)(H + (size_t)grow * kOUT + tx * 4) = w;
        }
    }
}

// 8 nodes/block, 32 lanes/node, 2ch/lane, unroll 4
__global__ void k_agg2(const bf16_t* __restrict__ H, const int* __restrict__ sorted,
                       const unsigned int* __restrict__ cursor, const unsigned int* __restrict__ deg,
                       const float* __restrict__ dinv, const void* __restrict__ bias,
                       const int* __restrict__ flags, float* __restrict__ Out) {
    int t = threadIdx.x;
    int local = t >> 5;
    int lane = t & 31;
    int c0 = lane * 2;
    int n = blockIdx.x * 8 + local;
    if (n >= kNN) return;
    const uint32_t* Hrow = (const uint32_t*)H;   // 32 words/row
    float dn = dinv[n];
    uint32_t hu = Hrow[(size_t)n * 32 + lane];
    float acc0 = lo16(hu), acc1 = hi16(hu);
    unsigned int e1 = cursor[n];
    unsigned int e = e1 - (deg[n] - 1u);
    int cnt = (int)(e1 - e);
    for (; cnt >= 4; cnt -= 4, e += 4) {
        int s0 = sorted[e], s1 = sorted[e + 1], s2 = sorted[e + 2], s3 = sorted[e + 3];
        uint32_t u0 = Hrow[(size_t)s0 * 32 + lane];
        uint32_t u1 = Hrow[(size_t)s1 * 32 + lane];
        uint32_t u2 = Hrow[(size_t)s2 * 32 + lane];
        uint32_t u3 = Hrow[(size_t)s3 * 32 + lane];
        acc0 += lo16(u0) + lo16(u1) + lo16(u2) + lo16(u3);
        acc1 += hi16(u0) + hi16(u1) + hi16(u2) + hi16(u3);
    }
    for (; cnt > 0; cnt--, e++) {
        uint32_t u = Hrow[(size_t)sorted[e] * 32 + lane];
        acc0 += lo16(u);
        acc1 += hi16(u);
    }
    float b0, b1v;
    if (flags[0]) { b0 = bf2f(((const bf16_t*)bias)[c0]); b1v = bf2f(((const bf16_t*)bias)[c0 + 1]); }
    else          { b0 = ((const float*)bias)[c0];        b1v = ((const float*)bias)[c0 + 1]; }
    float2 o; o.x = acc0 * dn + b0; o.y = acc1 * dn + b1v;
    *(float2*)(Out + (size_t)n * kOUT + c0) = o;
}

__global__ void k_stat2(const float* __restrict__ A2, float* __restrict__ stats) {
    int c = threadIdx.x & 63;
    int r0 = threadIdx.x >> 6;
    int chunk = (kNN + gridDim.x - 1) / gridDim.x;
    int nbeg = blockIdx.x * chunk;
    int nend = nbeg + chunk; if (nend > kNN) nend = kNN;
    float s0 = 0.f, s1 = 0.f;
    for (int n = nbeg + r0; n < nend; n += 4) {
        float v = A2[(size_t)n * kOUT + c];
        s0 += v; s1 += v * v;
    }
    atomicAdd(&stats[256 + c], s0);
    atomicAdd(&stats[320 + c], s1);
}

__global__ void k_out(const float* __restrict__ A2, const float* __restrict__ stats,
                      const int* __restrict__ batch, const void* __restrict__ gamma,
                      const void* __restrict__ beta, const int* __restrict__ flags,
                      bf16_t* __restrict__ out) {
    int wid = threadIdx.x >> 6;
    int lane = threadIdx.x & 63;
    int i = blockIdx.x * 4 + wid;
    if (i >= kNB) return;
    int n = batch[i];
    int c = lane;
    float mu = stats[256 + c] * (1.f / kNN);
    float var = stats[320 + c] * (1.f / kNN) - mu * mu;
    float g, b;
    if (flags[0]) { g = bf2f(((const bf16_t*)gamma)[c]); b = bf2f(((const bf16_t*)beta)[c]); }
    else          { g = ((const float*)gamma)[c];        b = ((const float*)beta)[c]; }
    float v = (A2[(size_t)n * kOUT + c] - mu) * rsqrtf(var + kEPS) * g + b;
    v = v > 0.f ? v : 0.f;
    float m = v;
    for (int o = 32; o; o >>= 1) m = fmaxf(m, __shfl_xor(m, o));
    float ex = expf(v - m);
    float s = ex;
    for (int o = 32; o; o >>= 1) s += __shfl_xor(s, o);
    float r = v - m - logf(s);
    if (flags[0]) out[(size_t)i * kOUT + c] = f2bf(r);
    else ((float*)out)[(size_t)i * kOUT + c] = r;
}

static inline size_t align_up(size_t x, size_t a) { return (x + a - 1) & ~(a - 1); }

extern "C" void kernel_launch(void* const* d_in, const int* in_sizes, int n_in,
                              void* d_out, int out_size, void* d_ws, size_t ws_size,
                              hipStream_t stream) {
    (void)in_sizes; (void)n_in; (void)out_size; (void)ws_size;
    const void* feat = d_in[0];
    const int* ei    = (const int*)d_in[1];
    const int* batch = (const int*)d_in[2];
    const void* W1   = d_in[3];
    const void* b1   = d_in[4];
    const void* g1   = d_in[5];
    const void* be1  = d_in[6];
    const void* W2   = d_in[7];
    const void* b2   = d_in[8];
    const void* g2   = d_in[9];
    const void* be2  = d_in[10];

    char* ws = (char*)d_ws;
    size_t o = 0;
    int*          flags  = (int*)(ws + o);          o = align_up(o + 32, 256);
    unsigned int* gtotal = (unsigned int*)(ws + o); o = align_up(o + 16, 256);
    unsigned int* deg    = (unsigned int*)(ws + o); o = align_up(o + (size_t)kNN * 4, 256);
    float*        dinv   = (float*)(ws + o);        o = align_up(o + (size_t)kNN * 4, 256);
    unsigned int* cursor = (unsigned int*)(ws + o); o = align_up(o + (size_t)kNN * 4, 256);
    float*        stats  = (float*)(ws + o);        o = align_up(o + 384 * 4, 256);
    int*          sorted = (int*)(ws + o);          o = align_up(o + (size_t)kNE * 4, 256);
    bf16_t*       h1     = (bf16_t*)(ws + o);       o = align_up(o + (size_t)kNN * kHID * 2, 256);
    float*        a1     = (float*)(ws + o);        o = align_up(o + (size_t)kNN * kHID * 4, 256);
    bf16_t*       x1 = h1;                            // h1 dead after agg1
    bf16_t*       h2 = (bf16_t*)a1;                   // a1 dead after bnrelu1
    float*        a2 = (float*)((char*)a1 + 16u * 1024u * 1024u);  // 16MB > 12.8MB h2

    bf16_t* outp = (bf16_t*)d_out;

    // graph build
    k_probe <<<1, 64, 0, stream>>>((const uint32_t*)feat, (const uint32_t*)ei, flags);
    k_setup <<<(kNN + 255) / 256, 256, 0, stream>>>(deg, stats, gtotal);
    k_deg   <<<(kNE + 255) / 256, 256, 0, stream>>>(ei, flags, deg);
    k_dinv  <<<(kNN + 255) / 256, 256, 0, stream>>>(deg, dinv);
    k_assign<<<(kNN + 255) / 256, 256, 0, stream>>>(deg, cursor, gtotal);
    k_bucket<<<(kNE + 255) / 256, 256, 0, stream>>>(ei, flags, cursor, sorted);

    // layer 1
    k_gemm1  <<<(kNN + 63) / 64, 256, 0, stream>>>(feat, W1, dinv, h1, flags);
    k_agg1   <<<(kNN + 3) / 4, 256, 0, stream>>>(h1, sorted, cursor, deg, dinv, b1, flags, a1);
    k_stat1  <<<256, 256, 0, stream>>>(a1, stats);
    k_bnrelu1<<<(kNN * kHID + 255) / 256, 256, 0, stream>>>(a1, stats, g1, be1, flags, x1);

    // layer 2
    k_gemm2<<<(kNN + 63) / 64, 256, 0, stream>>>(x1, W2, dinv, h2, flags);
    k_agg2 <<<(kNN + 7) / 8, 256, 0, stream>>>(h2, sorted, cursor, deg, dinv, b2, flags, a2);
    k_stat2<<<256, 256, 0, stream>>>(a2, stats);

    // gather + BN2 + relu + log_softmax
    k_out<<<(kNB + 3) / 4, 256, 0, stream>>>(a2, stats, batch, g2, be2, flags, outp);
}